// Round 3
// baseline (34189.984 us; speedup 1.0000x reference)
//
#include <hip/hip_runtime.h>
#include <hip/hip_bf16.h>

typedef unsigned short ushort_t;
typedef __attribute__((ext_vector_type(8))) short bf16x8;
typedef __attribute__((ext_vector_type(4))) float f32x4;

#define T_DIM 128
#define B_DIM 512
#define DIN 512
#define H_DIM 512
#define DM 256
#define HYP 256
#define L_DIM 100

__device__ __forceinline__ float bf2f(ushort_t u) {
    return __uint_as_float(((unsigned)u) << 16);
}
__device__ __forceinline__ ushort_t f2bf(float f) {
    unsigned u = __float_as_uint(f);
    unsigned r = (u + 0x7fffu + ((u >> 16) & 1u)) >> 16;
    return (ushort_t)r;
}
__device__ __forceinline__ float sigmoidf_(float x) {
    return 1.0f / (1.0f + __expf(-x));
}
__device__ __forceinline__ float fixf(float v) {
    if (!(v == v)) return 0.f;
    return fminf(fmaxf(v, -65504.f), 65504.f);
}

// ---------------------------------------------------------------------------
// dtype detector: valid bf16 never has exponent 0xFF; f32 read as ushorts does.
// ---------------------------------------------------------------------------
__global__ __launch_bounds__(256) void detect_kernel(const ushort_t* x, int nscan, int* flag) {
    __shared__ int found;
    if (threadIdx.x == 0) found = 0;
    __syncthreads();
    int f = 0;
    for (int i = threadIdx.x; i < nscan; i += 256) {
        unsigned u = x[i];
        if ((u & 0x7F80u) == 0x7F80u) f = 1;
    }
    if (f) atomicOr(&found, 1);
    __syncthreads();
    if (threadIdx.x == 0) *flag = found;
}

struct IngestP {
    const void* src[21];
    ushort_t* dst[21];
    int n[21];
    long total;
    const int* flag;
};

__global__ __launch_bounds__(256) void ingest_all(IngestP p) {
    int f = *p.flag;
    long idx0 = (long)blockIdx.x * 256 + threadIdx.x;
    long stride = (long)gridDim.x * 256;
    for (long idx = idx0; idx < p.total; idx += stride) {
        long r = idx;
#pragma unroll 1
        for (int t = 0; t < 21; t++) {
            if (r < p.n[t]) {
                p.dst[t][r] = f ? f2bf(((const float*)p.src[t])[r])
                               : ((const ushort_t*)p.src[t])[r];
                break;
            }
            r -= p.n[t];
        }
    }
}

__global__ __launch_bounds__(256) void zero_hhat(void* outbase, const int* flagp) {
    long i = 34078720 + (long)blockIdx.x * 256 + threadIdx.x;
    if (*flagp) ((float*)outbase)[i] = 0.f;
    else        ((ushort_t*)outbase)[i] = 0;
}

// ---------------------------------------------------------------------------
// Phase-A GEMM (unchanged from round 2): 128x128 tile, 4 waves, BK=32.
// ---------------------------------------------------------------------------
struct GP {
    const ushort_t* A1; const ushort_t* A2;
    const ushort_t* W1; const ushort_t* W2;
    long lda1, lda2, ldw1, ldw2;
    int K1, wc1, wc2, Nsplit, K, mode;
    const ushort_t* bias; ushort_t* outb; long ldo;
};

__global__ __launch_bounds__(256) void gemm_bt(GP g) {
    __shared__ __attribute__((aligned(16))) ushort_t As[128 * 40];
    __shared__ __attribute__((aligned(16))) ushort_t Bs[128 * 40];
    int tid  = threadIdx.x;
    int lane = tid & 63, wave = tid >> 6;
    int wm = (wave & 1) * 64, wn = (wave >> 1) * 64;
    int ml = lane & 15, quad = lane >> 4;
    long rowA0 = (long)blockIdx.x * 128;
    long rowW0 = (long)blockIdx.y * 128;
    int arow = tid >> 2, acol = (tid & 3) * 8;

    f32x4 acc[4][4];
#pragma unroll
    for (int i = 0; i < 4; i++)
#pragma unroll
        for (int j = 0; j < 4; j++) acc[i][j] = (f32x4){0.f, 0.f, 0.f, 0.f};

    for (int k0 = 0; k0 < g.K; k0 += 32) {
        uint4 av[2], wv[2];
#pragma unroll
        for (int s = 0; s < 2; s++) {
            int r = arow + s * 64;
            int k = k0 + acol;
            const ushort_t* asrc = (k < g.K1)
                ? g.A1 + (rowA0 + r) * g.lda1 + k
                : g.A2 + (rowA0 + r) * g.lda2 + (k - g.K1);
            av[s] = *(const uint4*)asrc;
            long n = rowW0 + r;
            const ushort_t* wsrc = (n < g.Nsplit)
                ? g.W1 + n * g.ldw1 + g.wc1 + k
                : g.W2 + (n - g.Nsplit) * g.ldw2 + g.wc2 + k;
            wv[s] = *(const uint4*)wsrc;
        }
        __syncthreads();
#pragma unroll
        for (int s = 0; s < 2; s++) {
            *(uint4*)&As[(arow + s * 64) * 40 + acol] = av[s];
            *(uint4*)&Bs[(arow + s * 64) * 40 + acol] = wv[s];
        }
        __syncthreads();
        bf16x8 af[4], bfm[4];
#pragma unroll
        for (int i = 0; i < 4; i++)
            af[i] = *(const bf16x8*)&As[(wm + i * 16 + ml) * 40 + quad * 8];
#pragma unroll
        for (int j = 0; j < 4; j++)
            bfm[j] = *(const bf16x8*)&Bs[(wn + j * 16 + ml) * 40 + quad * 8];
#pragma unroll
        for (int i = 0; i < 4; i++)
#pragma unroll
            for (int j = 0; j < 4; j++)
                acc[i][j] = __builtin_amdgcn_mfma_f32_16x16x32_bf16(af[i], bfm[j], acc[i][j], 0, 0, 0);
    }

#pragma unroll
    for (int i = 0; i < 4; i++) {
#pragma unroll
        for (int j = 0; j < 4; j++) {
            long rb = rowA0 + wm + i * 16 + quad * 4;
            long cn = rowW0 + wn + j * 16 + ml;
#pragma unroll
            for (int r = 0; r < 4; r++) {
                float v = acc[i][j][r];
                long rr = rb + r;
                if (g.bias) v += bf2f(g.bias[cn]);
                g.outb[rr * g.ldo + cn] = f2bf(v);
            }
        }
    }
}

// ---------------------------------------------------------------------------
// Attention (unchanged from round 2)
// ---------------------------------------------------------------------------
__global__ __launch_bounds__(256) void attn_kernel(const ushort_t* q, const ushort_t* kmat,
                                                   const ushort_t* meta, const int* inp,
                                                   ushort_t* att) {
    int b = blockIdx.x;
    __shared__ __attribute__((aligned(16))) ushort_t klds[L_DIM * 264];
    __shared__ float qlds[256];
    __shared__ float sc[L_DIM];
    __shared__ int msk[L_DIM];
    __shared__ float inv_s;
    int tid = threadIdx.x;

    for (int idx = tid; idx < L_DIM * 32; idx += 256) {
        int r = idx >> 5, c8 = (idx & 31) * 8;
        *(uint4*)&klds[r * 264 + c8] = *(const uint4*)&kmat[((long)b * L_DIM + r) * 256 + c8];
    }
    if (tid < L_DIM) msk[tid] = inp[b * L_DIM + tid];

    for (int t = 0; t < T_DIM; t++) {
        __syncthreads();
        qlds[tid] = bf2f(q[((long)t * B_DIM + b) * 256 + tid]);
        __syncthreads();
        if (tid < 2 * L_DIM) {
            int l = tid >> 1, half = tid & 1;
            const ushort_t* kr = &klds[l * 264 + half * 128];
            const float* qp = &qlds[half * 128];
            float s = 0.f;
            for (int j = 0; j < 128; j++) s += qp[j] * bf2f(kr[j]);
            s += __shfl_xor(s, 1);
            if (half == 0) sc[l] = (msk[l] == 0) ? -1000000000.0f : s * 0.0625f;
        }
        __syncthreads();
        if (tid < 64) {
            float s1 = sc[tid];
            float s2 = (tid + 64 < L_DIM) ? sc[tid + 64] : -1e30f;
            float mx = fmaxf(s1, s2);
            for (int o = 1; o < 64; o <<= 1) mx = fmaxf(mx, __shfl_xor(mx, o));
            float e1 = __expf(s1 - mx);
            float e2 = (tid + 64 < L_DIM) ? __expf(s2 - mx) : 0.f;
            float tot = e1 + e2;
            for (int o = 1; o < 64; o <<= 1) tot += __shfl_xor(tot, o);
            sc[tid] = e1;
            if (tid + 64 < L_DIM) sc[tid + 64] = e2;
            if (tid == 0) inv_s = 1.0f / tot;
        }
        __syncthreads();
        float a = 0.f;
        const ushort_t* mb = &meta[(long)b * L_DIM * 256 + tid];
        for (int l = 0; l < L_DIM; l++) a += sc[l] * bf2f(mb[(long)l * 256]);
        a *= inv_s;
        att[((long)t * B_DIM + b) * 256 + tid] = f2bf(a);
    }
}

// ---------------------------------------------------------------------------
// Precompute C[kind,k] and dbias (unchanged)
// ---------------------------------------------------------------------------
__global__ __launch_bounds__(256) void call_precompute(const ushort_t* Wdh, const ushort_t* Wdx,
                                                       const ushort_t* Wdb, const ushort_t* Wzh,
                                                       const ushort_t* Wzx, const ushort_t* Wzb,
                                                       ushort_t* Call) {
    int bk = blockIdx.x;
    int kind = bk >> 2, kk = bk & 3;
    int h0 = blockIdx.y * 64;
    int m0 = blockIdx.z * 64;
    const ushort_t* Wd = (kind == 0) ? Wdh : ((kind == 1) ? Wdx : Wdb);
    const ushort_t* Wz = (kind == 0) ? Wzh : ((kind == 1) ? Wzx : Wzb);
    __shared__ __attribute__((aligned(16))) ushort_t dt[64 * 72];
    __shared__ __attribute__((aligned(16))) ushort_t zt[64 * 72];
    int tid = threadIdx.x;
    int ty = tid >> 4, tx = tid & 15;
    float acc[4][4] = {};
    for (int z0 = 0; z0 < 256; z0 += 64) {
        __syncthreads();
        for (int idx = tid; idx < 512; idx += 256) {
            int r = idx >> 3, c8 = (idx & 7) * 8;
            *(uint4*)&dt[r * 72 + c8] = *(const uint4*)&Wd[((long)(kk * 512 + h0 + r)) * 256 + z0 + c8];
            *(uint4*)&zt[r * 72 + c8] = *(const uint4*)&Wz[((long)(kk * 256 + z0 + r)) * 256 + m0 + c8];
        }
        __syncthreads();
        for (int z = 0; z < 64; z++) {
            float a[4], bb[4];
#pragma unroll
            for (int i = 0; i < 4; i++) a[i] = bf2f(dt[(ty * 4 + i) * 72 + z]);
#pragma unroll
            for (int j = 0; j < 4; j++) bb[j] = bf2f(zt[z * 72 + tx * 4 + j]);
#pragma unroll
            for (int i = 0; i < 4; i++)
#pragma unroll
                for (int j = 0; j < 4; j++) acc[i][j] += a[i] * bb[j];
        }
    }
#pragma unroll
    for (int i = 0; i < 4; i++)
#pragma unroll
        for (int j = 0; j < 4; j++)
            Call[((long)(kind * 2048 + kk * 512 + h0 + ty * 4 + i)) * 256 + m0 + tx * 4 + j] = f2bf(acc[i][j]);
}

__global__ __launch_bounds__(256) void dbias_kernel(const ushort_t* Wdh, const ushort_t* Wdx,
                                                    const ushort_t* bzh, const ushort_t* bzx,
                                                    const ushort_t* bdb, float* dbias) {
    int n = blockIdx.x * 256 + threadIdx.x;
    int kind = n >> 11, kk = (n >> 9) & 3, h = n & 511;
    float s = 0.f;
    if (kind == 2) {
        s = bf2f(bdb[kk * 512 + h]);
    } else {
        const ushort_t* Wd = (kind == 0) ? Wdh : Wdx;
        const ushort_t* bz = (kind == 0) ? bzh : bzx;
        for (int z = 0; z < 256; z++)
            s += bf2f(Wd[((long)(kk * 512 + h)) * 256 + z]) * bf2f(bz[kk * 256 + z]);
    }
    dbias[n] = s;
}

// ---------------------------------------------------------------------------
// Persistent dataflow scan kernel: all 128 steps in one launch.
// Stages per step: S1 [merged|wh] = h @ Wcat^T (64x64 tiles, 288 items; +wx
// tiles 256 items if !full), S2 dall = merged @ C^T (768 items), S3 elementwise
// LN+LSTM (512 items). Per-slab counters give fine-grained cross-stage sync:
//   kind 0 c_mg[t][slab] tgt 4 | 1 c_wh tgt 32 | 2 c_d tgt 96 | 3 c_h tgt 64
//   kind 4 c_wx tgt 32
// Deadlock-free: every block's item list is (t, stage)-ordered.
// ---------------------------------------------------------------------------
struct SP {
    const ushort_t *x, *pre, *Wm, *w_h, *w_x, *callb, *ln_g, *ln_b, *wxall;
    const float* dbias;
    ushort_t *hbf, *mgd, *wxpp;
    float *cf, *whf, *dall;
    int* cnt;
    void* outb;
    const int* flagp;
    int full;
};

#define CNT(p, kind, t, slab) ((p).cnt[((kind) * T_DIM + (t)) * 8 + (slab)])

__device__ __forceinline__ void release_inc(int* ptr) {
    __hip_atomic_fetch_add(ptr, 1, __ATOMIC_RELEASE, __HIP_MEMORY_SCOPE_AGENT);
}
__device__ __forceinline__ void acquire_wait(int* ptr, int target) {
    while (__hip_atomic_load(ptr, __ATOMIC_ACQUIRE, __HIP_MEMORY_SCOPE_AGENT) < target)
        __builtin_amdgcn_s_sleep(2);
}

// 64x64 tile GEMM: 4 waves in 2x2, each 32x32 via 2x2 mfma_16x16x32 frags.
__device__ __forceinline__ void tile64(const ushort_t* A, long lda,
                                       const ushort_t* W, long ldw, int K,
                                       ushort_t* As, ushort_t* Bs,
                                       f32x4 acc[2][2], int tid) {
    int lane = tid & 63, wave = tid >> 6;
    int wm = (wave & 1) * 32, wn = (wave >> 1) * 32;
    int ml = lane & 15, quad = lane >> 4;
    int row = tid >> 2, col8 = (tid & 3) * 8;
#pragma unroll
    for (int i = 0; i < 2; i++)
#pragma unroll
        for (int j = 0; j < 2; j++) acc[i][j] = (f32x4){0.f, 0.f, 0.f, 0.f};
    for (int k0 = 0; k0 < K; k0 += 32) {
        uint4 av = *(const uint4*)(A + (long)row * lda + k0 + col8);
        uint4 wv = *(const uint4*)(W + (long)row * ldw + k0 + col8);
        __syncthreads();
        *(uint4*)&As[row * 40 + col8] = av;
        *(uint4*)&Bs[row * 40 + col8] = wv;
        __syncthreads();
        bf16x8 af[2], bfm[2];
#pragma unroll
        for (int i = 0; i < 2; i++)
            af[i] = *(const bf16x8*)&As[(wm + i * 16 + ml) * 40 + quad * 8];
#pragma unroll
        for (int j = 0; j < 2; j++)
            bfm[j] = *(const bf16x8*)&Bs[(wn + j * 16 + ml) * 40 + quad * 8];
#pragma unroll
        for (int i = 0; i < 2; i++)
#pragma unroll
            for (int j = 0; j < 2; j++)
                acc[i][j] = __builtin_amdgcn_mfma_f32_16x16x32_bf16(af[i], bfm[j], acc[i][j], 0, 0, 0);
    }
}

__global__ __launch_bounds__(256, 2) void scan_kernel(SP p) {
    __shared__ __attribute__((aligned(16))) ushort_t As[64 * 40];
    __shared__ __attribute__((aligned(16))) ushort_t Bs[64 * 40];
    __shared__ float yln[2048];
    int tid = threadIdx.x, bid = blockIdx.x, nb = gridDim.x;
    int lane = tid & 63, wave = tid >> 6;
    int wm = (wave & 1) * 32, wn = (wave >> 1) * 32;
    int ml = lane & 15, quad = lane >> 4;
    f32x4 acc[2][2];

    for (int t = 0; t < T_DIM; t++) {
        // ---- Stage 1: [merged|wh] tiles (288) + wx tiles (256, !full only) ----
        int n_s1 = 288 + (p.full ? 0 : 256);
        for (int it = bid; it < n_s1; it += nb) {
            if (it < 288) {
                int slab = it / 36, ct = it % 36;
                int rb0 = slab * 64;
                if (tid == 0 && t > 0) acquire_wait(&CNT(p, 3, t - 1, slab), 64);
                __syncthreads();
                const ushort_t* A = p.hbf + (long)rb0 * 512;
                if (ct < 4) {
                    int cb0 = ct * 64;
                    tile64(A, 512, p.Wm + (long)cb0 * 1280 + 768, 1280, 512, As, Bs, acc, tid);
                    const ushort_t* pr = p.pre + ((long)t * B_DIM) * 256;
#pragma unroll
                    for (int i = 0; i < 2; i++)
#pragma unroll
                        for (int j = 0; j < 2; j++)
#pragma unroll
                            for (int r = 0; r < 4; r++) {
                                int lr = wm + i * 16 + quad * 4 + r;
                                int lc = wn + j * 16 + ml;
                                float v = acc[i][j][r] + bf2f(pr[(long)(rb0 + lr) * 256 + cb0 + lc]);
                                v = v > 0.f ? v : 0.f;
                                p.mgd[(long)(rb0 + lr) * 256 + cb0 + lc] = f2bf(v);
                            }
                    __syncthreads();
                    if (tid == 0) release_inc(&CNT(p, 0, t, slab));
                } else {
                    int cb0 = ct * 64 - 256;  // wh col base 0..1983
                    tile64(A, 512, p.w_h + (long)cb0 * 512, 512, 512, As, Bs, acc, tid);
#pragma unroll
                    for (int i = 0; i < 2; i++)
#pragma unroll
                        for (int j = 0; j < 2; j++)
#pragma unroll
                            for (int r = 0; r < 4; r++) {
                                int lr = wm + i * 16 + quad * 4 + r;
                                int lc = wn + j * 16 + ml;
                                p.whf[(long)(rb0 + lr) * 2048 + cb0 + lc] = acc[i][j][r];
                            }
                    __syncthreads();
                    if (tid == 0) release_inc(&CNT(p, 1, t, slab));
                }
            } else {
                int it2 = it - 288;
                int slab = it2 >> 5, ct = it2 & 31;
                int rb0 = slab * 64, cb0 = ct * 64;
                if (tid == 0 && t >= 2) acquire_wait(&CNT(p, 3, t - 2, slab), 64);
                __syncthreads();
                const ushort_t* A = p.x + ((long)t * B_DIM + rb0) * 512;
                tile64(A, 512, p.w_x + (long)cb0 * 512, 512, 512, As, Bs, acc, tid);
                ushort_t* wdst = p.wxpp + (long)(t & 1) * B_DIM * 2048;
#pragma unroll
                for (int i = 0; i < 2; i++)
#pragma unroll
                    for (int j = 0; j < 2; j++)
#pragma unroll
                        for (int r = 0; r < 4; r++) {
                            int lr = wm + i * 16 + quad * 4 + r;
                            int lc = wn + j * 16 + ml;
                            wdst[(long)(rb0 + lr) * 2048 + cb0 + lc] = f2bf(acc[i][j][r]);
                        }
                __syncthreads();
                if (tid == 0) release_inc(&CNT(p, 4, t, slab));
            }
        }
        // ---- Stage 2: dall tiles (768) ----
        for (int it = bid; it < 768; it += nb) {
            int slab = it / 96, ct = it % 96;
            int rb0 = slab * 64, cb0 = ct * 64;
            if (tid == 0) acquire_wait(&CNT(p, 0, t, slab), 4);
            __syncthreads();
            tile64(p.mgd + (long)rb0 * 256, 256, p.callb + (long)cb0 * 256, 256, 256,
                   As, Bs, acc, tid);
#pragma unroll
            for (int i = 0; i < 2; i++)
#pragma unroll
                for (int j = 0; j < 2; j++)
#pragma unroll
                    for (int r = 0; r < 4; r++) {
                        int lr = wm + i * 16 + quad * 4 + r;
                        int lc = wn + j * 16 + ml;
                        p.dall[(long)(rb0 + lr) * 6144 + cb0 + lc] =
                            acc[i][j][r] + p.dbias[cb0 + lc];
                    }
            __syncthreads();
            if (tid == 0) release_inc(&CNT(p, 2, t, slab));
        }
        // ---- Stage 3: elementwise + LN + LSTM (512 items, one per b) ----
        for (int b = bid; b < B_DIM; b += nb) {
            int slab = b >> 6;
            if (tid == 0) {
                acquire_wait(&CNT(p, 1, t, slab), 32);
                acquire_wait(&CNT(p, 2, t, slab), 96);
                if (!p.full) acquire_wait(&CNT(p, 4, t, slab), 32);
            }
            __syncthreads();
            const float* db = p.dall + (long)b * 6144;
            const float* whb = p.whf + (long)b * 2048;
            const ushort_t* wxb = (p.full ? p.wxall + (long)t * B_DIM * 2048
                                          : p.wxpp + (long)(t & 1) * B_DIM * 2048)
                                  + (long)b * 2048;
            int w = tid >> 6;
            float y[8];
            float sum = 0.f, ss = 0.f;
#pragma unroll
            for (int j = 0; j < 8; j++) {
                int h = lane + j * 64;
                int n = w * 512 + h;
                float v = db[n] * whb[n] + db[2048 + n] * bf2f(wxb[n]) + db[4096 + n];
                v = fixf(v);
                y[j] = v;
                sum += v;
                ss += v * v;
            }
            for (int o = 1; o < 64; o <<= 1) {
                sum += __shfl_xor(sum, o);
                ss += __shfl_xor(ss, o);
            }
            float mu = sum * (1.f / 512.f);
            float var = ss * (1.f / 512.f) - mu * mu;
            float rstd = rsqrtf(fmaxf(var, 0.f) + 1e-5f);
#pragma unroll
            for (int j = 0; j < 8; j++) {
                int h = lane + j * 64;
                float g = bf2f(p.ln_g[w * 512 + h]);
                float bb = bf2f(p.ln_b[w * 512 + h]);
                yln[w * 512 + h] = (y[j] - mu) * rstd * g + bb;
            }
            __syncthreads();
            int f = *p.flagp;
            int last = (t == T_DIM - 1) ? 1 : 0;
#pragma unroll
            for (int s = 0; s < 2; s++) {
                int h = tid + s * 256;
                float iv = yln[h], fv = yln[512 + h], gv = yln[1024 + h], ov = yln[1536 + h];
                long ci = (long)b * 512 + h;
                float cold = p.cf[ci];
                float cn = sigmoidf_(fv) * cold + sigmoidf_(iv) * tanhf(gv);
                float hn = sigmoidf_(ov) * tanhf(cn);
                p.cf[ci] = cn;
                p.hbf[ci] = f2bf(hn);
                long oo = (long)t * B_DIM * H_DIM + ci;
                if (f) {
                    float* of = (float*)p.outb;
                    of[oo] = hn;
                    if (last) { of[33554432 + ci] = hn; of[33816576 + ci] = cn; }
                } else {
                    ushort_t* ob = (ushort_t*)p.outb;
                    ob[oo] = f2bf(hn);
                    if (last) { ob[33554432 + ci] = f2bf(hn); ob[33816576 + ci] = f2bf(cn); }
                }
            }
            __syncthreads();
            if (tid == 0) release_inc(&CNT(p, 3, t, slab));
        }
    }
}

// ---------------------------------------------------------------------------
extern "C" void kernel_launch(void* const* d_in, const int* in_sizes, int n_in,
                              void* d_out, int out_size, void* d_ws, size_t ws_size,
                              hipStream_t stream) {
    const int* inp = (const int*)d_in[2];

    size_t off = 0;
    char* wsb = (char*)d_ws;
    auto alloc = [&](size_t bytes) -> void* {
        off = (off + 255) & ~(size_t)255;
        void* p = wsb + off;
        off += bytes;
        return p;
    };

    int* flagp = (int*)alloc(256);

    static const int fidx[21] = {0,1,3,4,5,6,7,8,9,10,11,12,13,14,15,16,17,18,19,20,21};
    IngestP ip{};
    long total = 0;
    ushort_t* canon[21];
    for (int t = 0; t < 21; t++) {
        int src_i = fidx[t];
        int n = in_sizes[src_i];
        canon[t] = (ushort_t*)alloc((size_t)n * 2);
        ip.src[t] = d_in[src_i];
        ip.dst[t] = canon[t];
        ip.n[t] = n;
        total += n;
    }
    ip.total = total;
    ip.flag = flagp;

    const ushort_t* x    = canon[0];
    const ushort_t* meta = canon[1];
    const ushort_t* Wq   = canon[2];
    const ushort_t* bq   = canon[3];
    const ushort_t* Wk   = canon[4];
    const ushort_t* bk   = canon[5];
    const ushort_t* Wm   = canon[6];
    const ushort_t* bm   = canon[7];
    const ushort_t* Wzh  = canon[8];
    const ushort_t* bzh  = canon[9];
    const ushort_t* Wzx  = canon[10];
    const ushort_t* bzx  = canon[11];
    const ushort_t* Wzb  = canon[12];
    const ushort_t* Wdh  = canon[13];
    const ushort_t* Wdx  = canon[14];
    const ushort_t* Wdb  = canon[15];
    const ushort_t* bdb  = canon[16];
    const ushort_t* w_h  = canon[17];
    const ushort_t* w_x  = canon[18];
    const ushort_t* ln_g = canon[19];
    const ushort_t* ln_b = canon[20];

    ushort_t* qb    = (ushort_t*)alloc(33554432);   // 65536 x 256 bf16
    ushort_t* kmb   = (ushort_t*)alloc(26214400);   // 51200 x 256 bf16
    ushort_t* attb  = (ushort_t*)alloc(33554432);   // 65536 x 256 bf16
    ushort_t* preb  = (ushort_t*)alloc(33554432);   // 65536 x 256 bf16
    ushort_t* callb = (ushort_t*)alloc(3145728);    // 6144 x 256 bf16
    float*    dbias = (float*)alloc(24576);         // 6144 f32
    ushort_t* hbf   = (ushort_t*)alloc(524288);     // 512 x 512 bf16
    float*    cf    = (float*)alloc(1048576);       // 512 x 512 f32
    ushort_t* mgd   = (ushort_t*)alloc(262144);     // 512 x 256 bf16
    float*    whf   = (float*)alloc(4194304);       // 512 x 2048 f32
    float*    dall  = (float*)alloc(12582912);      // 512 x 6144 f32
    int*      cnt   = (int*)alloc(20480);           // 5 x 128 x 8 int
    ushort_t* wxpp  = (ushort_t*)alloc(4194304);    // 2 x 512 x 2048 bf16
    size_t base_end = (off + 255) & ~(size_t)255;
    bool full = (base_end + 268435456ull) <= ws_size;
    ushort_t* wxb = full ? (ushort_t*)alloc(268435456ull) : nullptr;

    detect_kernel<<<dim3(1), 256, 0, stream>>>((const ushort_t*)d_in[0], 262144, flagp);
    ingest_all<<<dim3(2048), 256, 0, stream>>>(ip);
    zero_hhat<<<dim3(1024), 256, 0, stream>>>(d_out, flagp);
    hipMemsetAsync(hbf, 0, 524288, stream);
    hipMemsetAsync(cf, 0, 1048576, stream);
    hipMemsetAsync(cnt, 0, 20480, stream);

    const int BIG = 1 << 30;

    // A1: kmat = meta @ Wk^T + bk
    {
        GP g{};
        g.A1 = meta; g.lda1 = 256; g.K1 = BIG; g.A2 = meta; g.lda2 = 256;
        g.W1 = Wk; g.ldw1 = 256; g.wc1 = 0; g.Nsplit = BIG; g.W2 = Wk; g.ldw2 = 256; g.wc2 = 0;
        g.K = 256; g.mode = 0; g.bias = bk; g.outb = kmb; g.ldo = 256;
        gemm_bt<<<dim3(400, 2), 256, 0, stream>>>(g);
    }
    // A2: q = x @ Wq^T + bq
    {
        GP g{};
        g.A1 = x; g.lda1 = 512; g.K1 = BIG; g.A2 = x; g.lda2 = 512;
        g.W1 = Wq; g.ldw1 = 512; g.wc1 = 0; g.Nsplit = BIG; g.W2 = Wq; g.ldw2 = 512; g.wc2 = 0;
        g.K = 512; g.mode = 0; g.bias = bq; g.outb = qb; g.ldo = 256;
        gemm_bt<<<dim3(512, 2), 256, 0, stream>>>(g);
    }
    // A3: attention
    attn_kernel<<<dim3(512), 256, 0, stream>>>(qb, kmb, meta, inp, attb);
    // A4: pre_merged = [x, att] @ Wm[:, :768]^T + bm
    {
        GP g{};
        g.A1 = x; g.lda1 = 512; g.K1 = 512; g.A2 = attb; g.lda2 = 256;
        g.W1 = Wm; g.ldw1 = 1280; g.wc1 = 0; g.Nsplit = BIG; g.W2 = Wm; g.ldw2 = 1280; g.wc2 = 0;
        g.K = 768; g.mode = 0; g.bias = bm; g.outb = preb; g.ldo = 256;
        gemm_bt<<<dim3(512, 2), 256, 0, stream>>>(g);
    }
    // A5: wx_all = x @ w_x^T (if workspace allows)
    if (full) {
        GP g{};
        g.A1 = x; g.lda1 = 512; g.K1 = BIG; g.A2 = x; g.lda2 = 512;
        g.W1 = w_x; g.ldw1 = 512; g.wc1 = 0; g.Nsplit = BIG; g.W2 = w_x; g.ldw2 = 512; g.wc2 = 0;
        g.K = 512; g.mode = 0; g.bias = nullptr; g.outb = wxb; g.ldo = 2048;
        gemm_bt<<<dim3(512, 16), 256, 0, stream>>>(g);
    }
    call_precompute<<<dim3(12, 8, 4), 256, 0, stream>>>(Wdh, Wdx, Wdb, Wzh, Wzx, Wzb, callb);
    dbias_kernel<<<dim3(24), 256, 0, stream>>>(Wdh, Wdx, bzh, bzx, bdb, dbias);

    // Persistent dataflow scan
    SP sp{};
    sp.x = x; sp.pre = preb; sp.Wm = Wm; sp.w_h = w_h; sp.w_x = w_x;
    sp.callb = callb; sp.ln_g = ln_g; sp.ln_b = ln_b; sp.wxall = wxb;
    sp.dbias = dbias; sp.hbf = hbf; sp.mgd = mgd; sp.wxpp = wxpp;
    sp.cf = cf; sp.whf = whf; sp.dall = dall; sp.cnt = cnt;
    sp.outb = d_out; sp.flagp = flagp; sp.full = full ? 1 : 0;

    int nCU = 256, occB = 2, dev = 0;
    hipGetDevice(&dev);
    hipDeviceGetAttribute(&nCU, hipDeviceAttributeMultiprocessorCount, dev);
    if (hipOccupancyMaxActiveBlocksPerMultiprocessor(&occB, scan_kernel, 256, 0) != hipSuccess
        || occB < 1) occB = 1;
    int grid = occB * nCU;
    if (grid > 512) grid = 512;

    void* args[] = {&sp};
    hipError_t e = hipLaunchCooperativeKernel((const void*)scan_kernel, dim3(grid), dim3(256),
                                              args, 0, stream);
    if (e != hipSuccess) {
        scan_kernel<<<dim3(grid), 256, 0, stream>>>(sp);
    }
}

// Round 4
// 13159.669 us; speedup vs baseline: 2.5981x; 2.5981x over previous
//
#include <hip/hip_runtime.h>
#include <hip/hip_bf16.h>

typedef unsigned short ushort_t;
typedef __attribute__((ext_vector_type(8))) short bf16x8;
typedef __attribute__((ext_vector_type(4))) float f32x4;

#define T_DIM 128
#define B_DIM 512
#define DIN 512
#define H_DIM 512
#define DM 256
#define HYP 256
#define L_DIM 100

__device__ __forceinline__ float bf2f(ushort_t u) {
    return __uint_as_float(((unsigned)u) << 16);
}
__device__ __forceinline__ ushort_t f2bf(float f) {
    unsigned u = __float_as_uint(f);
    unsigned r = (u + 0x7fffu + ((u >> 16) & 1u)) >> 16;
    return (ushort_t)r;
}
__device__ __forceinline__ float sigmoidf_(float x) {
    return 1.0f / (1.0f + __expf(-x));
}
__device__ __forceinline__ float fixf(float v) {
    if (!(v == v)) return 0.f;
    return fminf(fmaxf(v, -65504.f), 65504.f);
}

// ---- coherence-point accessors: relaxed agent atomics (sc1; bypass L1/local L2,
// NO buffer_inv / buffer_wbl2 emitted) ----
__device__ __forceinline__ unsigned cload_u32(const unsigned* p) {
    return __hip_atomic_load(p, __ATOMIC_RELAXED, __HIP_MEMORY_SCOPE_AGENT);
}
__device__ __forceinline__ void cstore_u32(unsigned* p, unsigned v) {
    __hip_atomic_store(p, v, __ATOMIC_RELAXED, __HIP_MEMORY_SCOPE_AGENT);
}
__device__ __forceinline__ float cload_f32(const float* p) {
    return __hip_atomic_load(p, __ATOMIC_RELAXED, __HIP_MEMORY_SCOPE_AGENT);
}
__device__ __forceinline__ void cstore_f32(float* p, float v) {
    __hip_atomic_store(p, v, __ATOMIC_RELAXED, __HIP_MEMORY_SCOPE_AGENT);
}
__device__ __forceinline__ float cload_bf16h(const unsigned* baseU, long elem) {
    unsigned u = cload_u32(baseU + (elem >> 1));
    return bf2f((ushort_t)((elem & 1) ? (u >> 16) : (u & 0xffffu)));
}
__device__ __forceinline__ void drain() { __builtin_amdgcn_s_waitcnt(0); }

// ---------------------------------------------------------------------------
__global__ __launch_bounds__(256) void detect_kernel(const ushort_t* x, int nscan, int* flag) {
    __shared__ int found;
    if (threadIdx.x == 0) found = 0;
    __syncthreads();
    int f = 0;
    for (int i = threadIdx.x; i < nscan; i += 256) {
        unsigned u = x[i];
        if ((u & 0x7F80u) == 0x7F80u) f = 1;
    }
    if (f) atomicOr(&found, 1);
    __syncthreads();
    if (threadIdx.x == 0) *flag = found;
}

struct IngestP {
    const void* src[21];
    ushort_t* dst[21];
    int n[21];
    long total;
    const int* flag;
};

__global__ __launch_bounds__(256) void ingest_all(IngestP p) {
    int f = *p.flag;
    long idx0 = (long)blockIdx.x * 256 + threadIdx.x;
    long stride = (long)gridDim.x * 256;
    for (long idx = idx0; idx < p.total; idx += stride) {
        long r = idx;
#pragma unroll 1
        for (int t = 0; t < 21; t++) {
            if (r < p.n[t]) {
                p.dst[t][r] = f ? f2bf(((const float*)p.src[t])[r])
                               : ((const ushort_t*)p.src[t])[r];
                break;
            }
            r -= p.n[t];
        }
    }
}

__global__ __launch_bounds__(256) void zero_hhat(void* outbase, const int* flagp) {
    long i = 34078720 + (long)blockIdx.x * 256 + threadIdx.x;
    if (*flagp) ((float*)outbase)[i] = 0.f;
    else        ((ushort_t*)outbase)[i] = 0;
}

// ---------------------------------------------------------------------------
// Phase-A GEMM: 128x128 tile, 4 waves, BK=32 (unchanged; correctness-proven).
// ---------------------------------------------------------------------------
struct GP {
    const ushort_t* A1; const ushort_t* A2;
    const ushort_t* W1; const ushort_t* W2;
    long lda1, lda2, ldw1, ldw2;
    int K1, wc1, wc2, Nsplit, K, mode;
    const ushort_t* bias; ushort_t* outb; long ldo;
};

__global__ __launch_bounds__(256) void gemm_bt(GP g) {
    __shared__ __attribute__((aligned(16))) ushort_t As[128 * 40];
    __shared__ __attribute__((aligned(16))) ushort_t Bs[128 * 40];
    int tid  = threadIdx.x;
    int lane = tid & 63, wave = tid >> 6;
    int wm = (wave & 1) * 64, wn = (wave >> 1) * 64;
    int ml = lane & 15, quad = lane >> 4;
    long rowA0 = (long)blockIdx.x * 128;
    long rowW0 = (long)blockIdx.y * 128;
    int arow = tid >> 2, acol = (tid & 3) * 8;

    f32x4 acc[4][4];
#pragma unroll
    for (int i = 0; i < 4; i++)
#pragma unroll
        for (int j = 0; j < 4; j++) acc[i][j] = (f32x4){0.f, 0.f, 0.f, 0.f};

    for (int k0 = 0; k0 < g.K; k0 += 32) {
        uint4 av[2], wv[2];
#pragma unroll
        for (int s = 0; s < 2; s++) {
            int r = arow + s * 64;
            int k = k0 + acol;
            const ushort_t* asrc = (k < g.K1)
                ? g.A1 + (rowA0 + r) * g.lda1 + k
                : g.A2 + (rowA0 + r) * g.lda2 + (k - g.K1);
            av[s] = *(const uint4*)asrc;
            long n = rowW0 + r;
            const ushort_t* wsrc = (n < g.Nsplit)
                ? g.W1 + n * g.ldw1 + g.wc1 + k
                : g.W2 + (n - g.Nsplit) * g.ldw2 + g.wc2 + k;
            wv[s] = *(const uint4*)wsrc;
        }
        __syncthreads();
#pragma unroll
        for (int s = 0; s < 2; s++) {
            *(uint4*)&As[(arow + s * 64) * 40 + acol] = av[s];
            *(uint4*)&Bs[(arow + s * 64) * 40 + acol] = wv[s];
        }
        __syncthreads();
        bf16x8 af[4], bfm[4];
#pragma unroll
        for (int i = 0; i < 4; i++)
            af[i] = *(const bf16x8*)&As[(wm + i * 16 + ml) * 40 + quad * 8];
#pragma unroll
        for (int j = 0; j < 4; j++)
            bfm[j] = *(const bf16x8*)&Bs[(wn + j * 16 + ml) * 40 + quad * 8];
#pragma unroll
        for (int i = 0; i < 4; i++)
#pragma unroll
            for (int j = 0; j < 4; j++)
                acc[i][j] = __builtin_amdgcn_mfma_f32_16x16x32_bf16(af[i], bfm[j], acc[i][j], 0, 0, 0);
    }

#pragma unroll
    for (int i = 0; i < 4; i++) {
#pragma unroll
        for (int j = 0; j < 4; j++) {
            long rb = rowA0 + wm + i * 16 + quad * 4;
            long cn = rowW0 + wn + j * 16 + ml;
#pragma unroll
            for (int r = 0; r < 4; r++) {
                float v = acc[i][j][r];
                long rr = rb + r;
                if (g.bias) v += bf2f(g.bias[cn]);
                g.outb[rr * g.ldo + cn] = f2bf(v);
            }
        }
    }
}

// ---------------------------------------------------------------------------
__global__ __launch_bounds__(256) void attn_kernel(const ushort_t* q, const ushort_t* kmat,
                                                   const ushort_t* meta, const int* inp,
                                                   ushort_t* att) {
    int b = blockIdx.x;
    __shared__ __attribute__((aligned(16))) ushort_t klds[L_DIM * 264];
    __shared__ float qlds[256];
    __shared__ float sc[L_DIM];
    __shared__ int msk[L_DIM];
    __shared__ float inv_s;
    int tid = threadIdx.x;

    for (int idx = tid; idx < L_DIM * 32; idx += 256) {
        int r = idx >> 5, c8 = (idx & 31) * 8;
        *(uint4*)&klds[r * 264 + c8] = *(const uint4*)&kmat[((long)b * L_DIM + r) * 256 + c8];
    }
    if (tid < L_DIM) msk[tid] = inp[b * L_DIM + tid];

    for (int t = 0; t < T_DIM; t++) {
        __syncthreads();
        qlds[tid] = bf2f(q[((long)t * B_DIM + b) * 256 + tid]);
        __syncthreads();
        if (tid < 2 * L_DIM) {
            int l = tid >> 1, half = tid & 1;
            const ushort_t* kr = &klds[l * 264 + half * 128];
            const float* qp = &qlds[half * 128];
            float s = 0.f;
            for (int j = 0; j < 128; j++) s += qp[j] * bf2f(kr[j]);
            s += __shfl_xor(s, 1);
            if (half == 0) sc[l] = (msk[l] == 0) ? -1000000000.0f : s * 0.0625f;
        }
        __syncthreads();
        if (tid < 64) {
            float s1 = sc[tid];
            float s2 = (tid + 64 < L_DIM) ? sc[tid + 64] : -1e30f;
            float mx = fmaxf(s1, s2);
            for (int o = 1; o < 64; o <<= 1) mx = fmaxf(mx, __shfl_xor(mx, o));
            float e1 = __expf(s1 - mx);
            float e2 = (tid + 64 < L_DIM) ? __expf(s2 - mx) : 0.f;
            float tot = e1 + e2;
            for (int o = 1; o < 64; o <<= 1) tot += __shfl_xor(tot, o);
            sc[tid] = e1;
            if (tid + 64 < L_DIM) sc[tid + 64] = e2;
            if (tid == 0) inv_s = 1.0f / tot;
        }
        __syncthreads();
        float a = 0.f;
        const ushort_t* mb = &meta[(long)b * L_DIM * 256 + tid];
        for (int l = 0; l < L_DIM; l++) a += sc[l] * bf2f(mb[(long)l * 256]);
        a *= inv_s;
        att[((long)t * B_DIM + b) * 256 + tid] = f2bf(a);
    }
}

// ---------------------------------------------------------------------------
__global__ __launch_bounds__(256) void call_precompute(const ushort_t* Wdh, const ushort_t* Wdx,
                                                       const ushort_t* Wdb, const ushort_t* Wzh,
                                                       const ushort_t* Wzx, const ushort_t* Wzb,
                                                       ushort_t* Call) {
    int bk = blockIdx.x;
    int kind = bk >> 2, kk = bk & 3;
    int h0 = blockIdx.y * 64;
    int m0 = blockIdx.z * 64;
    const ushort_t* Wd = (kind == 0) ? Wdh : ((kind == 1) ? Wdx : Wdb);
    const ushort_t* Wz = (kind == 0) ? Wzh : ((kind == 1) ? Wzx : Wzb);
    __shared__ __attribute__((aligned(16))) ushort_t dt[64 * 72];
    __shared__ __attribute__((aligned(16))) ushort_t zt[64 * 72];
    int tid = threadIdx.x;
    int ty = tid >> 4, tx = tid & 15;
    float acc[4][4] = {};
    for (int z0 = 0; z0 < 256; z0 += 64) {
        __syncthreads();
        for (int idx = tid; idx < 512; idx += 256) {
            int r = idx >> 3, c8 = (idx & 7) * 8;
            *(uint4*)&dt[r * 72 + c8] = *(const uint4*)&Wd[((long)(kk * 512 + h0 + r)) * 256 + z0 + c8];
            *(uint4*)&zt[r * 72 + c8] = *(const uint4*)&Wz[((long)(kk * 256 + z0 + r)) * 256 + m0 + c8];
        }
        __syncthreads();
        for (int z = 0; z < 64; z++) {
            float a[4], bb[4];
#pragma unroll
            for (int i = 0; i < 4; i++) a[i] = bf2f(dt[(ty * 4 + i) * 72 + z]);
#pragma unroll
            for (int j = 0; j < 4; j++) bb[j] = bf2f(zt[z * 72 + tx * 4 + j]);
#pragma unroll
            for (int i = 0; i < 4; i++)
#pragma unroll
                for (int j = 0; j < 4; j++) acc[i][j] += a[i] * bb[j];
        }
    }
#pragma unroll
    for (int i = 0; i < 4; i++)
#pragma unroll
        for (int j = 0; j < 4; j++)
            Call[((long)(kind * 2048 + kk * 512 + h0 + ty * 4 + i)) * 256 + m0 + tx * 4 + j] = f2bf(acc[i][j]);
}

__global__ __launch_bounds__(256) void dbias_kernel(const ushort_t* Wdh, const ushort_t* Wdx,
                                                    const ushort_t* bzh, const ushort_t* bzx,
                                                    const ushort_t* bdb, float* dbias) {
    int n = blockIdx.x * 256 + threadIdx.x;
    int kind = n >> 11, kk = (n >> 9) & 3, h = n & 511;
    float s = 0.f;
    if (kind == 2) {
        s = bf2f(bdb[kk * 512 + h]);
    } else {
        const ushort_t* Wd = (kind == 0) ? Wdh : Wdx;
        const ushort_t* bz = (kind == 0) ? bzh : bzx;
        for (int z = 0; z < 256; z++)
            s += bf2f(Wd[((long)(kk * 512 + h)) * 256 + z]) * bf2f(bz[kk * 256 + z]);
    }
    dbias[n] = s;
}

// ---------------------------------------------------------------------------
// Persistent scan. Sync: relaxed agent atomics only (no cache-maintenance ops);
// intermediates through coherence point via relaxed atomic dword ld/st.
// Counters: kind 0 mgd tgt4 | 1 wh tgt32 | 2 dall tgt96 | 3 h tgt64 | 4 wx tgt32.
// ---------------------------------------------------------------------------
struct SP {
    const ushort_t *x, *pre, *Wm, *w_h, *w_x, *callb, *ln_g, *ln_b, *wxall;
    const float* dbias;
    unsigned *hbfU, *mgdU, *wxppU;
    float *cf, *whf, *dall;
    int* cnt;
    void* outb;
    const int* flagp;
    int full;
};

#define CNT(p, kind, t, slab) ((p).cnt[((kind) * T_DIM + (t)) * 8 + (slab)])

__device__ __forceinline__ void release_cnt(int* ptr) {
    __hip_atomic_fetch_add(ptr, 1, __ATOMIC_RELAXED, __HIP_MEMORY_SCOPE_AGENT);
}
__device__ __forceinline__ void wait_cnt(int* ptr, int target) {
    while (__hip_atomic_load(ptr, __ATOMIC_RELAXED, __HIP_MEMORY_SCOPE_AGENT) < target)
        __builtin_amdgcn_s_sleep(2);
    __asm__ __volatile__("" ::: "memory");
}

// 64x64 tile GEMM. AM=0: A normal bf16 (uint4); AM=1: A coherent bf16 (4x u32).
template <int AM>
__device__ __forceinline__ void tile64(const void* Abase, long ldaE,
                                       const ushort_t* W, long ldw, int K,
                                       ushort_t* As, ushort_t* Bs,
                                       f32x4 acc[2][2], int tid) {
    int lane = tid & 63, wave = tid >> 6;
    int wm = (wave & 1) * 32, wn = (wave >> 1) * 32;
    int ml = lane & 15, quad = lane >> 4;
    int row = tid >> 2, col8 = (tid & 3) * 8;
#pragma unroll
    for (int i = 0; i < 2; i++)
#pragma unroll
        for (int j = 0; j < 2; j++) acc[i][j] = (f32x4){0.f, 0.f, 0.f, 0.f};

    uint4 av, wv;
    {
        if (AM == 0) {
            av = *(const uint4*)((const ushort_t*)Abase + (long)row * ldaE + col8);
        } else {
            const unsigned* A = (const unsigned*)Abase + (long)row * (ldaE >> 1) + (col8 >> 1);
            av.x = cload_u32(A); av.y = cload_u32(A + 1);
            av.z = cload_u32(A + 2); av.w = cload_u32(A + 3);
        }
        wv = *(const uint4*)(W + (long)row * ldw + col8);
    }
    for (int k0 = 0; k0 < K; k0 += 32) {
        __syncthreads();
        *(uint4*)&As[row * 40 + col8] = av;
        *(uint4*)&Bs[row * 40 + col8] = wv;
        __syncthreads();
        if (k0 + 32 < K) {
            int k = k0 + 32;
            if (AM == 0) {
                av = *(const uint4*)((const ushort_t*)Abase + (long)row * ldaE + k + col8);
            } else {
                const unsigned* A = (const unsigned*)Abase + (long)row * (ldaE >> 1) + ((k + col8) >> 1);
                av.x = cload_u32(A); av.y = cload_u32(A + 1);
                av.z = cload_u32(A + 2); av.w = cload_u32(A + 3);
            }
            wv = *(const uint4*)(W + (long)row * ldw + k + col8);
        }
        bf16x8 af[2], bfm[2];
#pragma unroll
        for (int i = 0; i < 2; i++)
            af[i] = *(const bf16x8*)&As[(wm + i * 16 + ml) * 40 + quad * 8];
#pragma unroll
        for (int j = 0; j < 2; j++)
            bfm[j] = *(const bf16x8*)&Bs[(wn + j * 16 + ml) * 40 + quad * 8];
#pragma unroll
        for (int i = 0; i < 2; i++)
#pragma unroll
            for (int j = 0; j < 2; j++)
                acc[i][j] = __builtin_amdgcn_mfma_f32_16x16x32_bf16(af[i], bfm[j], acc[i][j], 0, 0, 0);
    }
}

__global__ __launch_bounds__(256, 2) void scan_kernel(SP p) {
    __shared__ __attribute__((aligned(16))) ushort_t As[64 * 40];
    __shared__ __attribute__((aligned(16))) ushort_t Bs[64 * 40];
    __shared__ float yln[2048];
    int tid = threadIdx.x, bid = blockIdx.x, nb = gridDim.x;
    int lane = tid & 63, wave = tid >> 6;
    int wm = (wave & 1) * 32, wn = (wave >> 1) * 32;
    int ml = lane & 15, quad = lane >> 4;
    f32x4 acc[2][2];

    for (int t = 0; t < T_DIM; t++) {
        // ---- Stage 1 ----
        int n_s1 = 288 + (p.full ? 0 : 256);
        for (int it = bid; it < n_s1; it += nb) {
            if (it < 288) {
                int slab = it / 36, ct = it % 36;
                int rb0 = slab * 64;
                if (tid == 0 && t > 0) wait_cnt(&CNT(p, 3, t - 1, slab), 64);
                __syncthreads();
                const unsigned* A = p.hbfU + (long)rb0 * 256;
                if (ct < 4) {
                    int cb0 = ct * 64;
                    tile64<1>(A, 512, p.Wm + (long)cb0 * 1280 + 768, 1280, 512, As, Bs, acc, tid);
                    const ushort_t* pr = p.pre + ((long)t * B_DIM + rb0) * 256 + cb0;
#pragma unroll
                    for (int i = 0; i < 2; i++)
#pragma unroll
                        for (int j = 0; j < 2; j++) {
                            int lc = wn + j * 16 + ml;
                            float fin[4], oth[4];
#pragma unroll
                            for (int r = 0; r < 4; r++) {
                                int lr = wm + i * 16 + quad * 4 + r;
                                float v = acc[i][j][r] + bf2f(pr[(long)lr * 256 + lc]);
                                fin[r] = v > 0.f ? v : 0.f;
                            }
#pragma unroll
                            for (int r = 0; r < 4; r++) oth[r] = __shfl_xor(fin[r], 1);
                            int cpair = cb0 + (lc & ~1);
                            int r0 = (lane & 1) ? 2 : 0;
#pragma unroll
                            for (int rr = 0; rr < 2; rr++) {
                                int r = r0 + rr;
                                float v0 = (lane & 1) ? oth[r] : fin[r];
                                float v1 = (lane & 1) ? fin[r] : oth[r];
                                unsigned pk = (unsigned)f2bf(v0) | ((unsigned)f2bf(v1) << 16);
                                int lr = wm + i * 16 + quad * 4 + r;
                                cstore_u32(p.mgdU + (long)(rb0 + lr) * 128 + (cpair >> 1), pk);
                            }
                        }
                    drain();
                    __syncthreads();
                    if (tid == 0) release_cnt(&CNT(p, 0, t, slab));
                } else {
                    int cb0 = ct * 64 - 256;
                    tile64<1>(A, 512, p.w_h + (long)cb0 * 512, 512, 512, As, Bs, acc, tid);
#pragma unroll
                    for (int i = 0; i < 2; i++)
#pragma unroll
                        for (int j = 0; j < 2; j++)
#pragma unroll
                            for (int r = 0; r < 4; r++) {
                                int lr = wm + i * 16 + quad * 4 + r;
                                int lc = wn + j * 16 + ml;
                                cstore_f32(p.whf + (long)(rb0 + lr) * 2048 + cb0 + lc, acc[i][j][r]);
                            }
                    drain();
                    __syncthreads();
                    if (tid == 0) release_cnt(&CNT(p, 1, t, slab));
                }
            } else {
                int it2 = it - 288;
                int slab = it2 >> 5, ct = it2 & 31;
                int rb0 = slab * 64, cb0 = ct * 64;
                if (tid == 0 && t >= 2) wait_cnt(&CNT(p, 3, t - 2, slab), 64);
                __syncthreads();
                const ushort_t* A = p.x + ((long)t * B_DIM + rb0) * 512;
                tile64<0>(A, 512, p.w_x + (long)cb0 * 512, 512, 512, As, Bs, acc, tid);
                unsigned* wdst = p.wxppU + (long)(t & 1) * B_DIM * 1024;
#pragma unroll
                for (int i = 0; i < 2; i++)
#pragma unroll
                    for (int j = 0; j < 2; j++) {
                        int lc = wn + j * 16 + ml;
                        float fin[4], oth[4];
#pragma unroll
                        for (int r = 0; r < 4; r++) fin[r] = acc[i][j][r];
#pragma unroll
                        for (int r = 0; r < 4; r++) oth[r] = __shfl_xor(fin[r], 1);
                        int cpair = cb0 + (lc & ~1);
                        int r0 = (lane & 1) ? 2 : 0;
#pragma unroll
                        for (int rr = 0; rr < 2; rr++) {
                            int r = r0 + rr;
                            float v0 = (lane & 1) ? oth[r] : fin[r];
                            float v1 = (lane & 1) ? fin[r] : oth[r];
                            unsigned pk = (unsigned)f2bf(v0) | ((unsigned)f2bf(v1) << 16);
                            int lr = wm + i * 16 + quad * 4 + r;
                            cstore_u32(wdst + (long)(rb0 + lr) * 1024 + (cpair >> 1), pk);
                        }
                    }
                drain();
                __syncthreads();
                if (tid == 0) release_cnt(&CNT(p, 4, t, slab));
            }
        }
        // ---- Stage 2: dall tiles (768) ----
        for (int it = bid; it < 768; it += nb) {
            int slab = it / 96, ct = it % 96;
            int rb0 = slab * 64, cb0 = ct * 64;
            if (tid == 0) wait_cnt(&CNT(p, 0, t, slab), 4);
            __syncthreads();
            tile64<1>(p.mgdU + (long)rb0 * 128, 256, p.callb + (long)cb0 * 256, 256, 256,
                      As, Bs, acc, tid);
#pragma unroll
            for (int i = 0; i < 2; i++)
#pragma unroll
                for (int j = 0; j < 2; j++)
#pragma unroll
                    for (int r = 0; r < 4; r++) {
                        int lr = wm + i * 16 + quad * 4 + r;
                        int lc = wn + j * 16 + ml;
                        cstore_f32(p.dall + (long)(rb0 + lr) * 6144 + cb0 + lc,
                                   acc[i][j][r] + p.dbias[cb0 + lc]);
                    }
            drain();
            __syncthreads();
            if (tid == 0) release_cnt(&CNT(p, 2, t, slab));
        }
        // ---- Stage 3: elementwise + LN + LSTM (512 items) ----
        for (int b = bid; b < B_DIM; b += nb) {
            int slab = b >> 6;
            if (tid == 0) {
                wait_cnt(&CNT(p, 1, t, slab), 32);
                wait_cnt(&CNT(p, 2, t, slab), 96);
                if (!p.full) wait_cnt(&CNT(p, 4, t, slab), 32);
            }
            __syncthreads();
            const float* db = p.dall + (long)b * 6144;
            const float* whb = p.whf + (long)b * 2048;
            int w = tid >> 6;
            float y[8];
            float sum = 0.f, ss = 0.f;
#pragma unroll
            for (int j = 0; j < 8; j++) {
                int h = lane + j * 64;
                int n = w * 512 + h;
                float wxv;
                if (p.full)
                    wxv = bf2f(p.wxall[((long)t * B_DIM + b) * 2048 + n]);
                else
                    wxv = cload_bf16h(p.wxppU + (long)(t & 1) * B_DIM * 1024, (long)b * 2048 + n);
                float v = cload_f32(db + n) * cload_f32(whb + n)
                        + cload_f32(db + 2048 + n) * wxv
                        + cload_f32(db + 4096 + n);
                v = fixf(v);
                y[j] = v;
                sum += v;
                ss += v * v;
            }
            for (int o = 1; o < 64; o <<= 1) {
                sum += __shfl_xor(sum, o);
                ss += __shfl_xor(ss, o);
            }
            float mu = sum * (1.f / 512.f);
            float var = ss * (1.f / 512.f) - mu * mu;
            float rstd = rsqrtf(fmaxf(var, 0.f) + 1e-5f);
#pragma unroll
            for (int j = 0; j < 8; j++) {
                int h = lane + j * 64;
                float g = bf2f(p.ln_g[w * 512 + h]);
                float bb = bf2f(p.ln_b[w * 512 + h]);
                yln[w * 512 + h] = (y[j] - mu) * rstd * g + bb;
            }
            __syncthreads();
            int f = *p.flagp;
            int last = (t == T_DIM - 1) ? 1 : 0;
            {
                int u = tid;  // handles h = 2u, 2u+1
                float hn2[2], cn2[2];
#pragma unroll
                for (int e = 0; e < 2; e++) {
                    int h = 2 * u + e;
                    float iv = yln[h], fv = yln[512 + h], gv = yln[1024 + h], ov = yln[1536 + h];
                    long ci = (long)b * 512 + h;
                    float cold = p.cf[ci];
                    float cn = sigmoidf_(fv) * cold + sigmoidf_(iv) * tanhf(gv);
                    float hn = sigmoidf_(ov) * tanhf(cn);
                    p.cf[ci] = cn;
                    hn2[e] = hn; cn2[e] = cn;
                    long oo = (long)t * B_DIM * H_DIM + ci;
                    if (f) {
                        float* of = (float*)p.outb;
                        of[oo] = hn;
                        if (last) { of[33554432 + ci] = hn; of[33816576 + ci] = cn; }
                    } else {
                        ushort_t* ob = (ushort_t*)p.outb;
                        ob[oo] = f2bf(hn);
                        if (last) { ob[33554432 + ci] = f2bf(hn); ob[33816576 + ci] = f2bf(cn); }
                    }
                }
                unsigned pk = (unsigned)f2bf(hn2[0]) | ((unsigned)f2bf(hn2[1]) << 16);
                cstore_u32(p.hbfU + (long)b * 256 + u, pk);
            }
            drain();
            __syncthreads();
            if (tid == 0) release_cnt(&CNT(p, 3, t, slab));
        }
    }
}

// ---------------------------------------------------------------------------
extern "C" void kernel_launch(void* const* d_in, const int* in_sizes, int n_in,
                              void* d_out, int out_size, void* d_ws, size_t ws_size,
                              hipStream_t stream) {
    const int* inp = (const int*)d_in[2];

    size_t off = 0;
    char* wsb = (char*)d_ws;
    auto alloc = [&](size_t bytes) -> void* {
        off = (off + 255) & ~(size_t)255;
        void* p = wsb + off;
        off += bytes;
        return p;
    };

    int* flagp = (int*)alloc(256);

    static const int fidx[21] = {0,1,3,4,5,6,7,8,9,10,11,12,13,14,15,16,17,18,19,20,21};
    IngestP ip{};
    long total = 0;
    ushort_t* canon[21];
    for (int t = 0; t < 21; t++) {
        int src_i = fidx[t];
        int n = in_sizes[src_i];
        canon[t] = (ushort_t*)alloc((size_t)n * 2);
        ip.src[t] = d_in[src_i];
        ip.dst[t] = canon[t];
        ip.n[t] = n;
        total += n;
    }
    ip.total = total;
    ip.flag = flagp;

    const ushort_t* x    = canon[0];
    const ushort_t* meta = canon[1];
    const ushort_t* Wq   = canon[2];
    const ushort_t* bq   = canon[3];
    const ushort_t* Wk   = canon[4];
    const ushort_t* bk   = canon[5];
    const ushort_t* Wm   = canon[6];
    const ushort_t* bm   = canon[7];
    const ushort_t* Wzh  = canon[8];
    const ushort_t* bzh  = canon[9];
    const ushort_t* Wzx  = canon[10];
    const ushort_t* bzx  = canon[11];
    const ushort_t* Wzb  = canon[12];
    const ushort_t* Wdh  = canon[13];
    const ushort_t* Wdx  = canon[14];
    const ushort_t* Wdb  = canon[15];
    const ushort_t* bdb  = canon[16];
    const ushort_t* w_h  = canon[17];
    const ushort_t* w_x  = canon[18];
    const ushort_t* ln_g = canon[19];
    const ushort_t* ln_b = canon[20];

    ushort_t* qb    = (ushort_t*)alloc(33554432);
    ushort_t* kmb   = (ushort_t*)alloc(26214400);
    ushort_t* attb  = (ushort_t*)alloc(33554432);
    ushort_t* preb  = (ushort_t*)alloc(33554432);
    ushort_t* callb = (ushort_t*)alloc(3145728);
    float*    dbias = (float*)alloc(24576);
    unsigned* hbfU  = (unsigned*)alloc(524288);    // 512x512 bf16 as u32 pairs
    float*    cf    = (float*)alloc(1048576);
    unsigned* mgdU  = (unsigned*)alloc(262144);    // 512x256 bf16 as u32 pairs
    float*    whf   = (float*)alloc(4194304);
    float*    dall  = (float*)alloc(12582912);
    int*      cnt   = (int*)alloc(20480);
    unsigned* wxppU = (unsigned*)alloc(4194304);   // 2 x 512x2048 bf16 as u32 pairs
    size_t base_end = (off + 255) & ~(size_t)255;
    bool full = (base_end + 268435456ull) <= ws_size;
    ushort_t* wxb = full ? (ushort_t*)alloc(268435456ull) : nullptr;

    detect_kernel<<<dim3(1), 256, 0, stream>>>((const ushort_t*)d_in[0], 32768, flagp);
    ingest_all<<<dim3(2048), 256, 0, stream>>>(ip);
    zero_hhat<<<dim3(1024), 256, 0, stream>>>(d_out, flagp);
    hipMemsetAsync(hbfU, 0, 524288, stream);
    hipMemsetAsync(cf, 0, 1048576, stream);
    hipMemsetAsync(cnt, 0, 20480, stream);

    const int BIG = 1 << 30;

    {   // kmat = meta @ Wk^T + bk
        GP g{};
        g.A1 = meta; g.lda1 = 256; g.K1 = BIG; g.A2 = meta; g.lda2 = 256;
        g.W1 = Wk; g.ldw1 = 256; g.wc1 = 0; g.Nsplit = BIG; g.W2 = Wk; g.ldw2 = 256; g.wc2 = 0;
        g.K = 256; g.mode = 0; g.bias = bk; g.outb = kmb; g.ldo = 256;
        gemm_bt<<<dim3(400, 2), 256, 0, stream>>>(g);
    }
    {   // q = x @ Wq^T + bq
        GP g{};
        g.A1 = x; g.lda1 = 512; g.K1 = BIG; g.A2 = x; g.lda2 = 512;
        g.W1 = Wq; g.ldw1 = 512; g.wc1 = 0; g.Nsplit = BIG; g.W2 = Wq; g.ldw2 = 512; g.wc2 = 0;
        g.K = 512; g.mode = 0; g.bias = bq; g.outb = qb; g.ldo = 256;
        gemm_bt<<<dim3(512, 2), 256, 0, stream>>>(g);
    }
    attn_kernel<<<dim3(512), 256, 0, stream>>>(qb, kmb, meta, inp, attb);
    {   // pre_merged = [x, att] @ Wm[:, :768]^T + bm
        GP g{};
        g.A1 = x; g.lda1 = 512; g.K1 = 512; g.A2 = attb; g.lda2 = 256;
        g.W1 = Wm; g.ldw1 = 1280; g.wc1 = 0; g.Nsplit = BIG; g.W2 = Wm; g.ldw2 = 1280; g.wc2 = 0;
        g.K = 768; g.mode = 0; g.bias = bm; g.outb = preb; g.ldo = 256;
        gemm_bt<<<dim3(512, 2), 256, 0, stream>>>(g);
    }
    if (full) {  // wx_all = x @ w_x^T
        GP g{};
        g.A1 = x; g.lda1 = 512; g.K1 = BIG; g.A2 = x; g.lda2 = 512;
        g.W1 = w_x; g.ldw1 = 512; g.wc1 = 0; g.Nsplit = BIG; g.W2 = w_x; g.ldw2 = 512; g.wc2 = 0;
        g.K = 512; g.mode = 0; g.bias = nullptr; g.outb = wxb; g.ldo = 2048;
        gemm_bt<<<dim3(512, 16), 256, 0, stream>>>(g);
    }
    call_precompute<<<dim3(12, 8, 4), 256, 0, stream>>>(Wdh, Wdx, Wdb, Wzh, Wzx, Wzb, callb);
    dbias_kernel<<<dim3(24), 256, 0, stream>>>(Wdh, Wdx, bzh, bzx, bdb, dbias);

    SP sp{};
    sp.x = x; sp.pre = preb; sp.Wm = Wm; sp.w_h = w_h; sp.w_x = w_x;
    sp.callb = callb; sp.ln_g = ln_g; sp.ln_b = ln_b; sp.wxall = wxb;
    sp.dbias = dbias; sp.hbfU = hbfU; sp.mgdU = mgdU; sp.wxppU = wxppU;
    sp.cf = cf; sp.whf = whf; sp.dall = dall; sp.cnt = cnt;
    sp.outb = d_out; sp.flagp = flagp; sp.full = full ? 1 : 0;

    int nCU = 256, occB = 2, dev = 0;
    hipGetDevice(&dev);
    hipDeviceGetAttribute(&nCU, hipDeviceAttributeMultiprocessorCount, dev);
    if (hipOccupancyMaxActiveBlocksPerMultiprocessor(&occB, scan_kernel, 256, 0) != hipSuccess
        || occB < 1) occB = 1;
    int grid = occB * nCU;
    if (grid > 512) grid = 512;

    void* args[] = {&sp};
    hipError_t e = hipLaunchCooperativeKernel((const void*)scan_kernel, dim3(grid), dim3(256),
                                              args, 0, stream);
    if (e != hipSuccess) {
        scan_kernel<<<dim3(grid), 256, 0, stream>>>(sp);
    }
}